// Round 1
// baseline (240.818 us; speedup 1.0000x reference)
//
#include <hip/hip_runtime.h>
#include <math.h>

#define S 128
#define KA 25
#define KL 25
#define PATCH (KA * KA)        // 625
#define FEAT (2 * PATCH)       // 1250  (C * KA * KA)
#define PI_F 3.14159265358979323846f

// d_ws layout (floats):
//   [0, 625)              normalized LRI_ENV
//   [640, 640+625)        AFF env (max is exactly 1 at center, no normalize)
//   [1280, 1280+16384)    lat0 = relu(raw_aff - ada)
//   [17664, 17664+4096)   per-block corr partials
#define WS_LRI 0
#define WS_AE 640
#define WS_LAT0 1280
#define WS_PART 17664

// ---------------------------------------------------------------------------
// Kernel 0: build both envelope tables ONCE.  Previously every one of the
// 16384 k_tiles_aff blocks recomputed the 625-entry AFF env with libm
// sqrtf+cosf (~half of that kernel's VALU work).  One block, ~3 us.
// Values are bit-identical to the old per-block computation.
// ---------------------------------------------------------------------------
__global__ __launch_bounds__(256) void k_init(float* __restrict__ ws) {
    __shared__ float s_tmp[PATCH];
    __shared__ float s_part[4];
    const int tid = threadIdx.x;
    const int lane = tid & 63;
    const int wv = tid >> 6;

    // AFF envelope: cos(d*pi/25)^2 * (d < 12.5); center value is exactly 1.
    for (int i = tid; i < PATCH; i += 256) {
        float di = (float)(i / KA) - 12.0f;
        float dj = (float)(i % KA) - 12.0f;
        float d = sqrtf(di * di + dj * dj);
        float v = 0.0f;
        if (d < 12.5f) {
            float c = cosf(d * (PI_F / 25.0f));
            v = c * c;
        }
        ws[WS_AE + i] = v;
    }

    // LRI envelope: cos(d*pi/25)^2 * (1 - inh) * (d < 12.5), normalized by max.
    float m = 0.0f;
    for (int i = tid; i < PATCH; i += 256) {
        float di = (float)(i / KL) - 12.0f;
        float dj = (float)(i % KL) - 12.0f;
        float d = sqrtf(di * di + dj * dj);
        float v = 0.0f;
        if (d < 12.5f) {
            float c1 = cosf(d * (PI_F / 25.0f));
            float inh = 0.0f;
            if (d < 4.5f) {
                float c2 = cosf(d * (PI_F / 9.0f));
                inh = c2 * c2;
            }
            v = c1 * c1 * (1.0f - inh);
        }
        s_tmp[i] = v;
        m = fmaxf(m, v);
    }
    for (int off = 32; off > 0; off >>= 1) m = fmaxf(m, __shfl_down(m, off));
    if (lane == 0) s_part[wv] = m;
    __syncthreads();
    float inv = 1.0f / fmaxf(fmaxf(s_part[0], s_part[1]),
                             fmaxf(s_part[2], s_part[3]));
    for (int i = tid; i < PATCH; i += 256) ws[WS_LRI + i] = s_tmp[i] * inv;
}

// ---------------------------------------------------------------------------
// Kernel 1: tiles + raw_aff (+ lat0).  One block (256 threads) per position l.
// AFF env is loaded from ws (3 coalesced loads) instead of recomputed.
// Scalar stride-256 loads/stores: tiles base byte offset is 4 mod 8
// (out + 32769 floats), so vector stores would be misaligned-split; scalar
// dwords are perfectly coalesced (256B/instr).  tiles stores are nontemporal:
// write-once, never re-read on device -> don't evict rfs/lw from L3
// (working set ~210 MB vs 256 MB L3).
// ---------------------------------------------------------------------------
__global__ __launch_bounds__(256) void k_tiles_aff(const float* __restrict__ x,
                                                   const float* __restrict__ rfs,
                                                   const float* __restrict__ ada,
                                                   float* __restrict__ raw_aff,
                                                   float* __restrict__ tiles,
                                                   float* __restrict__ ws) {
    __shared__ float s_ae[PATCH];
    __shared__ float s_part[4];
    const int tid = threadIdx.x;
    const int lane = tid & 63;
    const int wv = tid >> 6;

    for (int i = tid; i < PATCH; i += 256) s_ae[i] = ws[WS_AE + i];
    __syncthreads();

    const int l = blockIdx.x;
    const int li = l >> 7;
    const int lj = l & 127;
    const long base = (long)l * FEAT;

    float acc = 0.0f;
#pragma unroll
    for (int c = 0; c < 2; ++c) {
        const float* __restrict__ xc = x + c * (152 * 152);
        const long cbase = base + (long)c * PATCH;
        for (int r = tid; r < PATCH; r += 256) {
            int ki = r / KA;
            int kj = r - ki * KA;
            float t = xc[(li + ki) * 152 + (lj + kj)] * s_ae[r];
            __builtin_nontemporal_store(t, &tiles[cbase + r]);
            acc += t * fmaxf(rfs[cbase + r], 0.0f);   // relu(rfs)
        }
    }

    for (int off = 32; off > 0; off >>= 1) acc += __shfl_down(acc, off);
    if (lane == 0) s_part[wv] = acc;
    __syncthreads();
    if (tid == 0) {
        float ra = s_part[0] + s_part[1] + s_part[2] + s_part[3];
        raw_aff[l] = ra;
        ws[WS_LAT0 + l] = fmaxf(ra - ada[l], 0.0f);   // lat0 for k_lat's gather
    }
}

// ---------------------------------------------------------------------------
// Kernel 2: final lat.  One wave per position, 4 per block (4096 blocks).
// lat_neg[l] = sum_f pad0(lat0)[nbr(l,f)] * le[f] * relu(lw[l,f])
// latf[l] = tanh(relu(lat0[l] - lat_neg + aff[l]))
// ---------------------------------------------------------------------------
__global__ __launch_bounds__(256) void k_lat(const float* __restrict__ raw_aff,
                                             const float* __restrict__ ada,
                                             const float* __restrict__ lw,
                                             float* __restrict__ latf,
                                             const float* __restrict__ ws) {
    __shared__ float s_le[PATCH];
    const int tid = threadIdx.x;
    for (int i = tid; i < PATCH; i += 256) s_le[i] = ws[WS_LRI + i];
    __syncthreads();

    const int lane = tid & 63;
    const int wv = tid >> 6;
    const int l = blockIdx.x * 4 + wv;
    const int li = l >> 7;
    const int lj = l & 127;
    const long base = (long)l * PATCH;
    const float* __restrict__ lat0 = ws + WS_LAT0;

    float acc = 0.0f;
    for (int f = lane; f < PATCH; f += 64) {
        int ki = f / KL;
        int kj = f - ki * KL;
        int ri = li + ki - 12;
        int rj = lj + kj - 12;
        float lv = 0.0f;
        if (ri >= 0 && ri < S && rj >= 0 && rj < S) lv = lat0[ri * S + rj];
        acc += lv * s_le[f] * fmaxf(lw[base + f], 0.0f);
    }
    for (int off = 32; off > 0; off >>= 1) acc += __shfl_down(acc, off);

    if (lane == 0) {
        float aff_l = raw_aff[l] - ada[l];
        float lat0_l = fmaxf(aff_l, 0.0f);
        float v = (lat0_l - acc) /* *STRENGTH=1 */ + aff_l;
        latf[l] = tanhf(fmaxf(v, 0.0f));
    }
}

// ---------------------------------------------------------------------------
// Kernel 3: per-block corr partials (no atomics, full parallelism).
// partial[b] = sum_{waves in b} latf[l] * sum_f padH(latf)[nbr] * le[f] * relu(lw)
// ---------------------------------------------------------------------------
__global__ __launch_bounds__(256) void k_corr(const float* __restrict__ latf,
                                              const float* __restrict__ lw,
                                              float* __restrict__ ws) {
    __shared__ float s_le[PATCH];
    __shared__ float s_part[4];
    const int tid = threadIdx.x;
    for (int i = tid; i < PATCH; i += 256) s_le[i] = ws[WS_LRI + i];
    __syncthreads();

    const int lane = tid & 63;
    const int wv = tid >> 6;
    const int l = blockIdx.x * 4 + wv;
    const int li = l >> 7;
    const int lj = l & 127;
    const long base = (long)l * PATCH;

    float acc = 0.0f;
    for (int f = lane; f < PATCH; f += 64) {
        int ki = f / KL;
        int kj = f - ki * KL;
        int ri = li + ki - 12;
        int rj = lj + kj - 12;
        float lv = 0.04f;  // HOMEO_TARGET padding
        if (ri >= 0 && ri < S && rj >= 0 && rj < S) lv = latf[ri * S + rj];
        acc += lv * s_le[f] * fmaxf(lw[base + f], 0.0f);
    }
    for (int off = 32; off > 0; off >>= 1) acc += __shfl_down(acc, off);

    if (lane == 0) s_part[wv] = acc * latf[l];
    __syncthreads();
    if (tid == 0)
        ws[WS_PART + blockIdx.x] = s_part[0] + s_part[1] + s_part[2] + s_part[3];
}

// ---------------------------------------------------------------------------
// Kernel 4: deterministic sum of 4096 partials -> corr scalar.
// ---------------------------------------------------------------------------
__global__ __launch_bounds__(256) void k_reduce(const float* __restrict__ ws,
                                                float* __restrict__ corr) {
    __shared__ float s_part[4];
    const int tid = threadIdx.x;
    const int lane = tid & 63;
    const int wv = tid >> 6;
    float acc = 0.0f;
    for (int i = tid; i < 4096; i += 256) acc += ws[WS_PART + i];
    for (int off = 32; off > 0; off >>= 1) acc += __shfl_down(acc, off);
    if (lane == 0) s_part[wv] = acc;
    __syncthreads();
    if (tid == 0) corr[0] = s_part[0] + s_part[1] + s_part[2] + s_part[3];
}

// ---------------------------------------------------------------------------
// d_out layout (flat, return order):
//   [0, 16384)              raw_aff   [1,1,128,128]
//   [16384, 32768)          lat       [1,1,128,128]
//   [32768]                 lat_correlations (scalar)
//   [32769, 32769+20480000) tiles     [16384, 1, 1250]
// ---------------------------------------------------------------------------
extern "C" void kernel_launch(void* const* d_in, const int* in_sizes, int n_in,
                              void* d_out, int out_size, void* d_ws, size_t ws_size,
                              hipStream_t stream) {
    const float* x   = (const float*)d_in[0];   // [1,2,152,152]
    const float* rfs = (const float*)d_in[1];   // [16384,1250,1]
    const float* lw  = (const float*)d_in[2];   // [16384,625,1]
    const float* ada = (const float*)d_in[3];   // [1,1,128,128]

    float* out      = (float*)d_out;
    float* raw_aff  = out;
    float* latf     = out + S * S;
    float* corr     = out + 2 * S * S;
    float* tiles    = out + 2 * S * S + 1;
    float* ws       = (float*)d_ws;

    k_init<<<1, 256, 0, stream>>>(ws);
    k_tiles_aff<<<S * S, 256, 0, stream>>>(x, rfs, ada, raw_aff, tiles, ws);
    k_lat<<<(S * S) / 4, 256, 0, stream>>>(raw_aff, ada, lw, latf, ws);
    k_corr<<<(S * S) / 4, 256, 0, stream>>>(latf, lw, ws);
    k_reduce<<<1, 256, 0, stream>>>(ws, corr);
}